// Round 3
// baseline (834.445 us; speedup 1.0000x reference)
//
#include <hip/hip_runtime.h>

// VectorQuantizer: z (8,64,16,64,64) f32, emb (512,64) f32.
// N = 524288, D = 64, K = 512.
// out flat = [ z_q_st (33554432 f32) | loss (1 f32) | indices (524288 f32) ]
//
// Bit-exact replication of the checker's np fp32 arithmetic (verified R3):
//   d[n,k] = fl( fmaf(-2, M_nk, zz_n) + ee_k ),  M_nk = sequential fma chain
//   c=0..63; zz/ee = numpy pairwise sum-of-squares (n=64 pattern);
//   argmin = strict <, ascending k.
//
// R8: R5-R7 proved runtime (~640us) is INVARIANT to the e-operand path
// (VMEM vs SMEM) and to every allocator knob (VGPR stuck at 48-60). The
// invariant is the single dependent 64-FMA chain per k: 64 x 4cyc latency
// = 256 cyc/k/wave vs 128 cyc issue -> a wave fills <=50% of issue slots,
// and the per-k s_load waits (a full 64-float row doesn't double-buffer in
// ~100 SGPRs) punch holes ~3 resident waves can't cover. Fix: process
// KT=4 codebook rows per tile with 4 INDEPENDENT interleaved fma chains.
// Each chain keeps its own strictly-sequential c-order (bit-exact), but
// the wave now always has 4 issueable FMAs (saturates the port at 1-2
// waves), e-loads batch 4 rows per c4 chunk (16 SGPRs live, prefetchable),
// and argmin/loop overhead amortizes 4x. Also: ws memset folded into
// vq_ee (one fewer dispatch).

#define NK       512
#define DD       64
#define LOSS_OFF 33554432
#define IDX_OFF  33554433
#define EE_FOFF  4            // float offset of ee[512] in ws (byte 16)

typedef float f32x4 __attribute__((ext_vector_type(4)));
#define CONST_AS __attribute__((address_space(4)))

// numpy pairwise_sum of squares, n=64: 8 strided accumulators combined
// ((r0+r1)+(r2+r3))+((r4+r5)+(r6+r7)); squares rounded separately.
// contract(off) keeps square and add separately rounded (replaces the old
// asm barriers, which blocked amdgpu-no-agpr inference).
__device__ __forceinline__ float np_sumsq64(const float* v) {
#pragma clang fp contract(off)
    float r[8];
    #pragma unroll
    for (int j = 0; j < 8; ++j) {
        float s = v[j] * v[j];
        r[j] = s;
    }
    #pragma unroll
    for (int i = 8; i < 64; i += 8) {
        #pragma unroll
        for (int j = 0; j < 8; ++j) {
            float s = v[i + j] * v[i + j];
            r[j] += s;
        }
    }
    return ((r[0] + r[1]) + (r[2] + r[3])) + ((r[4] + r[5]) + (r[6] + r[7]));
}

__global__ void vq_ee(const float* __restrict__ emb, float* __restrict__ ws) {
    const int k = blockIdx.x * 256 + threadIdx.x;      // grid 2 x 256
    if (blockIdx.x == 0 && threadIdx.x == 0) {         // replaces hipMemsetAsync
        ((double*)ws)[0] = 0.0;
        ((double*)ws)[1] = 0.0;
    }
    float row[DD];
    const float* er = emb + k * DD;
    #pragma unroll
    for (int c = 0; c < DD; ++c) row[c] = er[c];
    ws[EE_FOFF + k] = np_sumsq64(row);
}

__global__ __launch_bounds__(256)
__attribute__((amdgpu_waves_per_eu(4, 6)))
void vq_main(const float* __restrict__ z, const float* __restrict__ emb,
             float* __restrict__ out, float* __restrict__ ws) {
    const int n  = blockIdx.x * 256 + threadIdx.x;     // grid 2048 x 256
    const int b  = n >> 16;
    const int sp = n & 65535;
    const float* zp = z + ((size_t)b << 22) + sp;

    float zr[DD];
    #pragma unroll
    for (int c = 0; c < DD; ++c) zr[c] = zp[(size_t)c << 16];
    const float zz = np_sumsq64(zr);

    // constant-address-space views -> s_load (scalar cache, SGPR destinations)
    const CONST_AS f32x4* e4  = (const CONST_AS f32x4*)emb;            // 16/row
    const CONST_AS float* eec = (const CONST_AS float*)(ws + EE_FOFF);

    float best = 3.4e38f;
    int   bi   = 0;

    #pragma unroll 1
    for (int k0 = 0; k0 < NK; k0 += 4) {
        const CONST_AS f32x4* r0 = e4 + ((k0 + 0) << 4);   // uniform rows
        const CONST_AS f32x4* r1 = e4 + ((k0 + 1) << 4);
        const CONST_AS f32x4* r2 = e4 + ((k0 + 2) << 4);
        const CONST_AS f32x4* r3 = e4 + ((k0 + 3) << 4);
        float m0 = 0.f, m1 = 0.f, m2 = 0.f, m3 = 0.f;  // 4 independent chains
        #pragma unroll
        for (int c4 = 0; c4 < 16; ++c4) {
            const f32x4 e0 = r0[c4];                   // 4 x s_load_dwordx4
            const f32x4 e1 = r1[c4];
            const f32x4 e2 = r2[c4];
            const f32x4 e3 = r3[c4];
            const float z0 = zr[c4 * 4 + 0];
            const float z1 = zr[c4 * 4 + 1];
            const float z2 = zr[c4 * 4 + 2];
            const float z3 = zr[c4 * 4 + 3];
            m0 = fmaf(z0, e0.x, m0); m1 = fmaf(z0, e1.x, m1);
            m2 = fmaf(z0, e2.x, m2); m3 = fmaf(z0, e3.x, m3);
            m0 = fmaf(z1, e0.y, m0); m1 = fmaf(z1, e1.y, m1);
            m2 = fmaf(z1, e2.y, m2); m3 = fmaf(z1, e3.y, m3);
            m0 = fmaf(z2, e0.z, m0); m1 = fmaf(z2, e1.z, m1);
            m2 = fmaf(z2, e2.z, m2); m3 = fmaf(z2, e3.z, m3);
            m0 = fmaf(z3, e0.w, m0); m1 = fmaf(z3, e1.w, m1);
            m2 = fmaf(z3, e2.w, m2); m3 = fmaf(z3, e3.w, m3);
        }
        const float d0 = fmaf(-2.f, m0, zz) + eec[k0 + 0];
        const float d1 = fmaf(-2.f, m1, zz) + eec[k0 + 1];
        const float d2 = fmaf(-2.f, m2, zz) + eec[k0 + 2];
        const float d3 = fmaf(-2.f, m3, zz) + eec[k0 + 3];
        // strict <, ascending k (order preserved)
        if (d0 < best) { best = d0; bi = k0 + 0; }
        if (d1 < best) { best = d1; bi = k0 + 1; }
        if (d2 < best) { best = d2; bi = k0 + 2; }
        if (d3 < best) { best = d3; bi = k0 + 3; }
    }

    // epilogue: gather z_q row (emb L1/L2-hot, divergent bi), coalesced writes
    float* op = out + ((size_t)b << 22) + sp;
    const float4* brow = (const float4*)(emb + bi * DD);
    float lsum = 0.f;
    #pragma unroll
    for (int c4 = 0; c4 < 16; ++c4) {
        float4 e = brow[c4];
        float eq[4] = { e.x, e.y, e.z, e.w };
        #pragma unroll
        for (int j = 0; j < 4; ++j) {
            const int c = c4 * 4 + j;
            float dd = eq[j] - zr[c];
            lsum = fmaf(dd, dd, lsum);
            op[(size_t)c << 16] = eq[j];
        }
    }
    out[IDX_OFF + n] = (float)bi;

    #pragma unroll
    for (int off = 32; off > 0; off >>= 1) lsum += __shfl_down(lsum, off);
    if ((threadIdx.x & 63) == 0)
        atomicAdd((double*)ws, (double)lsum);          // fp64 final accumulation
}

__global__ void vq_finalize(const float* __restrict__ ws, float* __restrict__ out) {
    out[LOSS_OFF] = (float)(((const double*)ws)[0] * (1.25 / 33554432.0));
}

extern "C" void kernel_launch(void* const* d_in, const int* in_sizes, int n_in,
                              void* d_out, int out_size, void* d_ws, size_t ws_size,
                              hipStream_t stream) {
    const float* z   = (const float*)d_in[0];
    const float* emb = (const float*)d_in[1];
    float* out = (float*)d_out;
    float* ws  = (float*)d_ws;

    vq_ee<<<dim3(2), dim3(256), 0, stream>>>(emb, ws);
    vq_main<<<dim3(2048), dim3(256), 0, stream>>>(z, emb, out, ws);
    vq_finalize<<<dim3(1), dim3(1), 0, stream>>>(ws, out);
}

// Round 5
// 730.258 us; speedup vs baseline: 1.1427x; 1.1427x over previous
//
#include <hip/hip_runtime.h>

// VectorQuantizer: z (8,64,16,64,64) f32, emb (512,64) f32.
// N = 524288, D = 64, K = 512.
// out flat = [ z_q_st (33554432 f32) | loss (1 f32) | indices (524288 f32) ]
//
// Bit-exact replication of the checker's np fp32 arithmetic (verified R3):
//   d[n,k] = fl( fmaf(-2, M_nk, zz_n) + ee_k ),  M_nk = sequential fma chain
//   c=0..63; zz/ee = numpy pairwise sum-of-squares (n=64 pattern);
//   argmin = strict <, ascending k.
//
// R10 == R9 resubmitted (R9 bench died on container acquisition, not the
// kernel — source audited: no hang/correctness hazard found).
//
// R9: structural change. R5-R8 established two dead ends:
//  (1) SMEM e-path: scalar loads return OUT OF ORDER -> every consumer needs
//      lgkmcnt(0) full drain -> no fine-grained pipelining; each k exposes
//      ~250cy of scalar-cache latency that 3-4 waves only marginally cover
//      (the invariant 640us).
//  (2) The allocator caps ARCH VGPRs at ~40-64 regardless of attributes and
//      shuttles overflow (zr!) through AGPRs (VGPR_Count 40-60 < zr's 64;
//      total ~124 matches the observed 4 waves/SIMD; ~1 v_accvgpr_read per
//      FMA matches the stable 2.3x VALU bloat).
// Fix: e-operands from LDS broadcast (uniform ds_read_b128: in-order,
// fine-grained lgkmcnt, conflict-free) staged 32KB/pass x 4 passes; TWO n
// rows per thread so each 16B e-read feeds 8 FMAs (DS/CU ~218us vs VALU
// ~245us, parallel pipes). ee[] also in LDS (an s_load per k would force a
// drain). Chain order per n unchanged -> bit-exact argmin.

#define NK       512
#define DD       64
#define LOSS_OFF 33554432
#define IDX_OFF  33554433
#define EE_FOFF  4            // float offset of ee[512] in ws (byte 16)

typedef float f32x4 __attribute__((ext_vector_type(4)));

// numpy pairwise_sum of squares, n=64: 8 strided accumulators combined
// ((r0+r1)+(r2+r3))+((r4+r5)+(r6+r7)); squares rounded separately
// (contract(off) keeps square and add separately rounded).
__device__ __forceinline__ float np_sumsq64(const float* v) {
#pragma clang fp contract(off)
    float r[8];
    #pragma unroll
    for (int j = 0; j < 8; ++j) {
        float s = v[j] * v[j];
        r[j] = s;
    }
    #pragma unroll
    for (int i = 8; i < 64; i += 8) {
        #pragma unroll
        for (int j = 0; j < 8; ++j) {
            float s = v[i + j] * v[i + j];
            r[j] += s;
        }
    }
    return ((r[0] + r[1]) + (r[2] + r[3])) + ((r[4] + r[5]) + (r[6] + r[7]));
}

__global__ void vq_ee(const float* __restrict__ emb, float* __restrict__ ws) {
    const int k = blockIdx.x * 256 + threadIdx.x;      // grid 2 x 256
    if (blockIdx.x == 0 && threadIdx.x == 0) {         // zero fp64 loss acc
        ((double*)ws)[0] = 0.0;
        ((double*)ws)[1] = 0.0;
    }
    float row[DD];
    const float* er = emb + k * DD;
    #pragma unroll
    for (int c = 0; c < DD; ++c) row[c] = er[c];
    ws[EE_FOFF + k] = np_sumsq64(row);
}

__global__ __launch_bounds__(256)
__attribute__((amdgpu_waves_per_eu(3, 3)))
void vq_main(const float* __restrict__ z, const float* __restrict__ emb,
             float* __restrict__ out, float* __restrict__ ws) {
    __shared__ f32x4 elds[2048];       // 32 KB: 128 emb rows per pass
    __shared__ float eelds[NK];        // 2 KB: ee[512], filled once

    const int tid = threadIdx.x;
    const int n0  = blockIdx.x * 512 + tid;            // grid 1024 x 256
    const int n1  = n0 + 256;                          // same b (512 | 65536)
    const int b   = n0 >> 16;
    const int sp  = n0 & 65535;
    const float* zp0 = z + ((size_t)b << 22) + sp;
    const float* zp1 = zp0 + 256;

    eelds[tid]       = ws[EE_FOFF + tid];
    eelds[tid + 256] = ws[EE_FOFF + tid + 256];

    float za[DD], zb[DD];                              // 128 VGPRs, resident
    #pragma unroll
    for (int c = 0; c < DD; ++c) za[c] = zp0[(size_t)c << 16];
    #pragma unroll
    for (int c = 0; c < DD; ++c) zb[c] = zp1[(size_t)c << 16];
    const float zz0 = np_sumsq64(za);
    const float zz1 = np_sumsq64(zb);

    const f32x4* eg = (const f32x4*)emb;

    float best0 = 3.4e38f, best1 = 3.4e38f;
    int   bi0   = 0,        bi1   = 0;

    #pragma unroll 1
    for (int p = 0; p < 4; ++p) {
        __syncthreads();                               // prev pass reads done
        #pragma unroll
        for (int r = 0; r < 8; ++r)                    // 32 KB coalesced fill
            elds[r * 256 + tid] = eg[p * 2048 + r * 256 + tid];
        __syncthreads();                               // fill visible

        #pragma unroll 1
        for (int kl = 0; kl < 128; ++kl) {
            float m0 = 0.f, m1 = 0.f;                  // 2 independent chains
            #pragma unroll
            for (int c4 = 0; c4 < 16; ++c4) {
                const f32x4 e = elds[kl * 16 + c4];    // uniform b128 broadcast
                const int c = c4 * 4;
                m0 = fmaf(za[c + 0], e.x, m0);  m1 = fmaf(zb[c + 0], e.x, m1);
                m0 = fmaf(za[c + 1], e.y, m0);  m1 = fmaf(zb[c + 1], e.y, m1);
                m0 = fmaf(za[c + 2], e.z, m0);  m1 = fmaf(zb[c + 2], e.z, m1);
                m0 = fmaf(za[c + 3], e.w, m0);  m1 = fmaf(zb[c + 3], e.w, m1);
            }
            const int k = p * 128 + kl;                // ascending global k
            const float ee = eelds[k];
            const float d0 = fmaf(-2.f, m0, zz0) + ee;
            const float d1 = fmaf(-2.f, m1, zz1) + ee;
            if (d0 < best0) { best0 = d0; bi0 = k; }   // strict <, ascending
            if (d1 < best1) { best1 = d1; bi1 = k; }
        }
    }

    // epilogue x2: gather z_q rows (emb L2-hot, divergent bi), coalesced writes
    float* op0 = out + ((size_t)b << 22) + sp;
    float* op1 = op0 + 256;
    const float4* br0 = (const float4*)(emb + bi0 * DD);
    const float4* br1 = (const float4*)(emb + bi1 * DD);
    float lsum = 0.f;
    #pragma unroll
    for (int c4 = 0; c4 < 16; ++c4) {
        float4 e0 = br0[c4];
        float4 e1 = br1[c4];
        float eq0[4] = { e0.x, e0.y, e0.z, e0.w };
        float eq1[4] = { e1.x, e1.y, e1.z, e1.w };
        #pragma unroll
        for (int j = 0; j < 4; ++j) {
            const int c = c4 * 4 + j;
            float da = eq0[j] - za[c];
            float db = eq1[j] - zb[c];
            lsum = fmaf(da, da, lsum);
            lsum = fmaf(db, db, lsum);
            op0[(size_t)c << 16] = eq0[j];
            op1[(size_t)c << 16] = eq1[j];
        }
    }
    out[IDX_OFF + n0] = (float)bi0;
    out[IDX_OFF + n1] = (float)bi1;

    #pragma unroll
    for (int off = 32; off > 0; off >>= 1) lsum += __shfl_down(lsum, off);
    if ((tid & 63) == 0)
        atomicAdd((double*)ws, (double)lsum);          // fp64 final accumulation
}

__global__ void vq_finalize(const float* __restrict__ ws, float* __restrict__ out) {
    out[LOSS_OFF] = (float)(((const double*)ws)[0] * (1.25 / 33554432.0));
}

extern "C" void kernel_launch(void* const* d_in, const int* in_sizes, int n_in,
                              void* d_out, int out_size, void* d_ws, size_t ws_size,
                              hipStream_t stream) {
    const float* z   = (const float*)d_in[0];
    const float* emb = (const float*)d_in[1];
    float* out = (float*)d_out;
    float* ws  = (float*)d_ws;

    vq_ee<<<dim3(2), dim3(256), 0, stream>>>(emb, ws);
    vq_main<<<dim3(1024), dim3(256), 0, stream>>>(z, emb, out, ws);
    vq_finalize<<<dim3(1), dim3(1), 0, stream>>>(ws, out);
}